// Round 4
// baseline (266.741 us; speedup 1.0000x reference)
//
#include <hip/hip_runtime.h>

#define B_ 32
#define M_ 8192
#define Q_ 64
#define D_ 128
#define MT 64
#define CHN 16                 // chunks per batch -> grid = B_*CHN = 512 (2 blocks/CU exact)
#define NT (M_ / (CHN * MT))   // 8 tiles per block (even, required by 2-deep pipeline)
#define LDP 72                 // u16 pitch of sP rows (144 B, 16B-aligned)
#define LDU 136                // u16 pitch of sU rows (272 B, 16B-aligned)
#define SAP 36                 // f32 pitch of sA/sC rows (144 B, 16B-aligned for b128)

typedef __attribute__((ext_vector_type(8))) short short8;
typedef __attribute__((ext_vector_type(4))) float floatx4;

// round-half-up f32->bf16, pack two into one u32 {hi=bf(b), lo=bf(a)}
__device__ __forceinline__ unsigned pkbf(float a, float b) {
  unsigned ua = __builtin_bit_cast(unsigned, a) + 0x8000u;
  unsigned ub = __builtin_bit_cast(unsigned, b) + 0x8000u;
  return __builtin_amdgcn_perm(ub, ua, 0x07060302u);
}

__device__ __forceinline__ short8 pack8(float4 a, float4 b) {
  union { unsigned u[4]; short8 v; } o;
  o.u[0] = pkbf(a.x, a.y); o.u[1] = pkbf(a.z, a.w);
  o.u[2] = pkbf(b.x, b.y); o.u[3] = pkbf(b.z, b.w);
  return o.v;
}

// non-temporal streaming loads: A and C have ZERO reuse -> do not pollute L2/MALL
__device__ __forceinline__ float4 nt4(const float* p) {
  floatx4 v = __builtin_nontemporal_load((const floatx4*)p);
  return make_float4(v[0], v[1], v[2], v[3]);
}

template <int CTRL>
__device__ __forceinline__ float dppadd(float x) {
  int y = __builtin_amdgcn_update_dpp(0, __builtin_bit_cast(int, x), CTRL, 0xF, 0xF, true);
  return x + __builtin_bit_cast(float, y);
}
__device__ __forceinline__ float rowsum16(float x) {  // sum across each 16-lane DPP row
  x = dppadd<0x128>(x); x = dppadd<0x124>(x);
  x = dppadd<0x122>(x); x = dppadd<0x121>(x);
  return x;
}

// LDS-only barrier: never drains vmcnt -> in-flight global loads keep flowing.
__device__ __forceinline__ void barrier_lds() {
  asm volatile("s_waitcnt lgkmcnt(0)\n\ts_barrier" ::: "memory");
}

template <bool ATOMIC>
__global__ __launch_bounds__(256, 2) void memn2n_main(
    const float* __restrict__ A, const float* __restrict__ U,
    const float* __restrict__ Cc, float* __restrict__ dst) {
  // Full-line 1024-B requests + 2-tile-deep register pipeline (~32 KB/wave in flight).
  // Lane-layout mismatch vs MFMA fragments is fixed by tiny wave-private LDS staging.
  __shared__ __align__(16) unsigned short sU[Q_ * LDU];     // 17408 B, u as bf16
  __shared__ __align__(16) unsigned short sP[2][Q_ * LDP];  // 18432 B, P^T exchange
  __shared__ __align__(16) float sA[4][16 * SAP];           //  9216 B, A transpose stage
  __shared__ __align__(16) float sC[4][32 * SAP];           // 18432 B, C transpose stage
                                                            // total 63488 B -> 2 blocks/CU

  const int tid  = threadIdx.x;
  const int lane = tid & 63;
  const int w    = tid >> 6;
  const int l15  = lane & 15;
  const int quad = (lane >> 4) & 3;
  const int lr   = lane >> 3;   // 0..7 row-within-group for full-line loads
  const int lc   = lane & 7;    // 0..7 16B-granule within a 128-B line

  const int blk = blockIdx.x;
  const int b   = blk / CHN;
  const int ch  = blk - b * CHN;

  const float* Abase = A + ((size_t)b * M_ + (size_t)ch * NT * MT) * D_;
  const float* Cbase = Cc + ((size_t)b * M_ + (size_t)ch * NT * MT) * D_;

  // full-line per-lane stream pointers:
  // A instr (ks,j2): rows 16w+8*j2+lr, bytes [128*ks + 16*lc, +16) -> 8 full lines
  // C instr (g):     rows 8g+lr, cols 32w + 4*lc (..+3)            -> 8 full lines
  const float* ApL = Abase + ((size_t)(16 * w + lr) * D_) + 4 * lc;
  const float* CpL = Cbase + ((size_t)lr * D_) + 32 * w + 4 * lc;

  float4 aR0[8], aR1[8];  // 64 VGPR: two tiles of A (this wave's 16 rows)
  float4 cR0[8], cR1[8];  // 64 VGPR: two tiles of C (this wave's 32 d-cols)

  // prologue: tiles 0 and 1 in flight (oldest first), then sU staging
#pragma unroll
  for (int ks = 0; ks < 4; ++ks) {
    aR0[2 * ks]     = nt4(ApL + 32 * ks);
    aR0[2 * ks + 1] = nt4(ApL + 32 * ks + 8 * (size_t)D_);
  }
#pragma unroll
  for (int g = 0; g < 8; ++g) cR0[g] = nt4(CpL + (size_t)(8 * g) * D_);
  {
    const float* Ap1 = ApL + (size_t)MT * D_;
    const float* Cp1 = CpL + (size_t)MT * D_;
#pragma unroll
    for (int ks = 0; ks < 4; ++ks) {
      aR1[2 * ks]     = nt4(Ap1 + 32 * ks);
      aR1[2 * ks + 1] = nt4(Ap1 + 32 * ks + 8 * (size_t)D_);
    }
#pragma unroll
    for (int g = 0; g < 8; ++g) cR1[g] = nt4(Cp1 + (size_t)(8 * g) * D_);
  }

  // ---- stage u (fp32 -> bf16) into sU cooperatively (one-time; cached loads, U is reused)
  {
    const float* ub = U + (size_t)b * Q_ * D_;
#pragma unroll
    for (int i = 0; i < 8; ++i) {
      int idx = tid + i * 256;  // 2048 float4s = 64 rows x 32
      int q = idx >> 5, c4 = idx & 31;
      float4 v = *(const float4*)(ub + q * D_ + c4 * 4);
      *(uint2*)&sU[q * LDU + c4 * 4] = make_uint2(pkbf(v.x, v.y), pkbf(v.z, v.w));
    }
  }

  barrier_lds();  // sU visible; A/C loads stay in flight

  float* const sAw = sA[w];
  float* const sCw = sC[w];

  floatx4 acc[2][4];
#pragma unroll
  for (int i = 0; i < 2; ++i)
#pragma unroll
    for (int j = 0; j < 4; ++j) acc[i][j] = (floatx4){0.f, 0.f, 0.f, 0.f};

  // one tile; prefetches tile tt+2 into the SAME register buffer (freed slot by slot)
#define TILE_BODY(tt, aRx, cRx)                                                      \
  do {                                                                               \
    floatx4 s1[4];                                                                   \
    _Pragma("unroll") for (int qs = 0; qs < 4; ++qs)                                 \
        s1[qs] = (floatx4){0.f, 0.f, 0.f, 0.f};                                      \
    _Pragma("unroll") for (int ks = 0; ks < 4; ++ks) {                               \
      *(float4*)&sAw[(0 + lr) * SAP + 4 * lc] = aRx[2 * ks];                         \
      *(float4*)&sAw[(8 + lr) * SAP + 4 * lc] = aRx[2 * ks + 1];                     \
      if ((tt) + 2 < NT) {                                                           \
        const float* An = ApL + (size_t)((tt) + 2) * MT * D_;                        \
        aRx[2 * ks]     = nt4(An + 32 * ks);                                         \
        aRx[2 * ks + 1] = nt4(An + 32 * ks + 8 * (size_t)D_);                        \
      }                                                                              \
      float4 x = *(const float4*)&sAw[l15 * SAP + 8 * quad];                         \
      float4 y = *(const float4*)&sAw[l15 * SAP + 8 * quad + 4];                     \
      short8 af = pack8(x, y);                                                       \
      _Pragma("unroll") for (int qs = 0; qs < 4; ++qs) {                             \
        short8 uq = *(const short8*)&sU[(16 * qs + l15) * LDU + 32 * ks + 8 * quad]; \
        s1[qs] = __builtin_amdgcn_mfma_f32_16x16x32_bf16(af, uq, s1[qs], 0, 0, 0);   \
      }                                                                              \
    }                                                                                \
    float pv[4][4];                                                                  \
    _Pragma("unroll") for (int rg = 0; rg < 4; ++rg) {                               \
      const float cst = 1.4426950408889634f;                                         \
      float e0 = exp2f(s1[0][rg] * cst), e1 = exp2f(s1[1][rg] * cst);                \
      float e2 = exp2f(s1[2][rg] * cst), e3 = exp2f(s1[3][rg] * cst);                \
      float sm = (e0 + e1) + (e2 + e3);                                              \
      sm = rowsum16(sm);                                                             \
      float inv = __builtin_amdgcn_rcpf(sm);                                         \
      pv[0][rg] = e0 * inv; pv[1][rg] = e1 * inv;                                    \
      pv[2][rg] = e2 * inv; pv[3][rg] = e3 * inv;                                    \
    }                                                                                \
    unsigned short* sPt = &sP[(tt) & 1][0];                                          \
    _Pragma("unroll") for (int qs = 0; qs < 4; ++qs)                                 \
      *(uint2*)&sPt[(16 * qs + l15) * LDP + 16 * w + 4 * quad] =                     \
          make_uint2(pkbf(pv[qs][0], pv[qs][1]), pkbf(pv[qs][2], pv[qs][3]));        \
    _Pragma("unroll") for (int g = 0; g < 4; ++g)                                    \
      *(float4*)&sCw[(8 * g + lr) * SAP + 4 * lc] = cRx[g];                          \
    if ((tt) + 2 < NT) {                                                             \
      const float* Cn = CpL + (size_t)((tt) + 2) * MT * D_;                          \
      _Pragma("unroll") for (int g = 0; g < 4; ++g)                                  \
        cRx[g] = nt4(Cn + (size_t)(8 * g) * D_);                                     \
    }                                                                                \
    barrier_lds();                                                                   \
    _Pragma("unroll") for (int ks = 0; ks < 2; ++ks) {                               \
      if (ks == 1) {                                                                 \
        _Pragma("unroll") for (int g = 4; g < 8; ++g)                                \
          *(float4*)&sCw[(8 * (g - 4) + lr) * SAP + 4 * lc] = cRx[g];                \
        if ((tt) + 2 < NT) {                                                         \
          const float* Cn = CpL + (size_t)((tt) + 2) * MT * D_;                      \
          _Pragma("unroll") for (int g = 4; g < 8; ++g)                              \
            cRx[g] = nt4(Cn + (size_t)(8 * g) * D_);                                 \
        }                                                                            \
      }                                                                              \
      short8 pa[4];                                                                  \
      _Pragma("unroll") for (int qs = 0; qs < 4; ++qs)                               \
        pa[qs] = *(const short8*)&sPt[(16 * qs + l15) * LDP + 32 * ks + 8 * quad];   \
      _Pragma("unroll") for (int ds = 0; ds < 2; ++ds) {                             \
        float cc[8];                                                                 \
        _Pragma("unroll") for (int j = 0; j < 8; ++j)                                \
          cc[j] = sCw[(8 * quad + j) * SAP + 16 * ds + l15];                         \
        union { unsigned u[4]; short8 v; } o;                                        \
        o.u[0] = pkbf(cc[0], cc[1]); o.u[1] = pkbf(cc[2], cc[3]);                    \
        o.u[2] = pkbf(cc[4], cc[5]); o.u[3] = pkbf(cc[6], cc[7]);                    \
        _Pragma("unroll") for (int qs = 0; qs < 4; ++qs)                             \
          acc[ds][qs] =                                                              \
              __builtin_amdgcn_mfma_f32_16x16x32_bf16(pa[qs], o.v, acc[ds][qs], 0, 0, 0); \
      }                                                                              \
    }                                                                                \
  } while (0)

  for (int t = 0; t < NT; t += 2) {
    TILE_BODY(t, aR0, cR0);
    TILE_BODY(t + 1, aR1, cR1);
  }
#undef TILE_BODY

  // epilogue: q = qs*16 + quad*4 + rg, d = l15 + 16*(2w+ds)
  if (ATOMIC) {
#pragma unroll
    for (int ds = 0; ds < 2; ++ds)
#pragma unroll
      for (int qs = 0; qs < 4; ++qs)
#pragma unroll
        for (int rg = 0; rg < 4; ++rg) {
          int q = qs * 16 + quad * 4 + rg;
          int d = l15 + 16 * (2 * w + ds);
          atomicAdd(&dst[((size_t)b * Q_ + q) * D_ + d], acc[ds][qs][rg]);
        }
  } else {
    float* pp = dst + (((size_t)ch * B_ + b) * Q_) * D_;
#pragma unroll
    for (int ds = 0; ds < 2; ++ds)
#pragma unroll
      for (int qs = 0; qs < 4; ++qs)
#pragma unroll
        for (int rg = 0; rg < 4; ++rg) {
          int q = qs * 16 + quad * 4 + rg;
          int d = l15 + 16 * (2 * w + ds);
          pp[q * D_ + d] = acc[ds][qs][rg];
        }
  }
}

// out[b,q,d] = u[b,q,:]·H[:,d] + sum_ch partial[ch,b,q,d]; chunks==0 -> u·H only
__global__ __launch_bounds__(128) void memn2n_reduce(
    const float* __restrict__ U, const float* __restrict__ H,
    const float* __restrict__ part, float* __restrict__ out, int chunks) {
  int bq = blockIdx.x;
  int b = bq >> 6, q = bq & 63;
  int d = threadIdx.x;
  __shared__ float su[D_];
  size_t row = ((size_t)b * Q_ + q) * D_;
  su[d] = U[row + d];
  __syncthreads();
  float acc = 0.f;
#pragma unroll 16
  for (int e = 0; e < D_; ++e) acc = fmaf(su[e], H[e * D_ + d], acc);
#pragma unroll 8
  for (int ch = 0; ch < chunks; ++ch)
    acc += part[(((size_t)ch * B_ + b) * Q_ + q) * D_ + d];
  out[row + d] = acc;
}

extern "C" void kernel_launch(void* const* d_in, const int* in_sizes, int n_in,
                              void* d_out, int out_size, void* d_ws, size_t ws_size,
                              hipStream_t stream) {
  const float* A  = (const float*)d_in[0];
  const float* U  = (const float*)d_in[1];
  const float* Cc = (const float*)d_in[2];
  const float* H  = (const float*)d_in[3];
  float* out = (float*)d_out;

  size_t part_bytes = (size_t)CHN * B_ * Q_ * D_ * sizeof(float);  // 16.8 MB
  if (ws_size >= part_bytes) {
    float* part = (float*)d_ws;
    memn2n_main<false><<<B_ * CHN, 256, 0, stream>>>(A, U, Cc, part);
    memn2n_reduce<<<B_ * Q_, 128, 0, stream>>>(U, H, part, out, CHN);
  } else {
    memn2n_reduce<<<B_ * Q_, 128, 0, stream>>>(U, H, nullptr, out, 0);
    memn2n_main<true><<<B_ * CHN, 256, 0, stream>>>(A, U, Cc, out);
  }
}